// Round 10
// baseline (330.817 us; speedup 1.0000x reference)
//
#include <hip/hip_runtime.h>
#include <math.h>

#define NEG_SLOPE_F 0.2f
#define NB   2048     // dst buckets
#define NSL  8        // slices (XCD count)

typedef __attribute__((ext_vector_type(8)))  short short8;
typedef __attribute__((ext_vector_type(16))) float f32x16;

static __device__ __forceinline__ float lrelu(float x) {
    return x > 0.f ? x : NEG_SLOPE_F * x;
}
static __device__ __forceinline__ unsigned f2bf(float f) {
    unsigned u = __float_as_uint(f);
    unsigned r = u + 0x7FFFu + ((u >> 16) & 1u);
    return r >> 16;
}
static __device__ __forceinline__ float bflo(unsigned w) { return __uint_as_float(w << 16); }
static __device__ __forceinline__ float bfhi(unsigned w) { return __uint_as_float(w & 0xFFFF0000u); }

static __device__ __forceinline__ int bucket_of(int d, int nps, float inv_nps) {
    int b = (int)((float)d * inv_nps);
    if (d < b * nps) --b;
    else if (d >= (b + 1) * nps) ++b;
    return b;
}

// ---------------- init: zero slice counters + W -> Wt bf16 (transposed) -----
__global__ void k_init(const float* __restrict__ W, unsigned short* __restrict__ Wt,
                       int* __restrict__ scnt) {
    int g = blockIdx.x * 256 + threadIdx.x;      // 64 blocks x 256 = 16384
    scnt[g] = 0;
    int c = g >> 7, k = g & 127;
    Wt[c * 128 + k] = (unsigned short)f2bf(W[k * 128 + c]);
}

// ---------------- count per (slice, bucket); slice = chunk&7 (deterministic)
__global__ void k_count(const int* __restrict__ ei, int E, int N, int nps, float inv_nps,
                        int* __restrict__ scnt, int chunkSize) {
    int rid = blockIdx.x;                         // 2048 chunks
    int sl = rid & 7;
    int total = E + N;
    int lo = rid * chunkSize;
    int hi = lo + chunkSize; if (hi > total) hi = total;
    for (int t = lo + (int)threadIdx.x; t < hi; t += 256) {
        int s, d;
        if (t < E) { s = ei[t]; d = ei[E + t]; }
        else       { s = t - E; d = s; }
        if ((unsigned)s >= (unsigned)N || (unsigned)d >= (unsigned)N) continue;
        int b = bucket_of(d, nps, inv_nps);
        atomicAdd(&scnt[sl * NB + b], 1);
    }
}

// ---------------- exclusive scan of 16384 counts -> sbase, scursor ----------
__global__ __launch_bounds__(1024) void k_scan(const int* __restrict__ scnt,
                                               int* __restrict__ sbase, int* __restrict__ scursor) {
    __shared__ int sm[1024];
    int t = threadIdx.x;
    int base = t * 16;
    int loc[16];
    int run = 0;
#pragma unroll
    for (int i = 0; i < 16; ++i) { loc[i] = run; run += scnt[base + i]; }
    sm[t] = run;
    __syncthreads();
    int acc = run;
    for (int off = 1; off < 1024; off <<= 1) {
        int o = (t >= (unsigned)off) ? sm[t - off] : 0;
        __syncthreads();
        acc += o;
        sm[t] = acc;
        __syncthreads();
    }
    int excl = acc - run;
#pragma unroll
    for (int i = 0; i < 16; ++i) {
        int v = excl + loc[i];
        sbase[base + i] = v;
        scursor[base + i] = v;
    }
}

// ---------------- fused: dense append (blocks [0,NB)) + MFMA GEMM ----------
// append: same chunk->slice mapping as k_count => exact offsets, no overflow.
// gemm: h_bf16 = bf16(x)@bf16(W) via mfma_f32_32x32x16_bf16, no LDS.
__global__ __launch_bounds__(256) void k_gemm_append(
        const float* __restrict__ x, const unsigned short* __restrict__ Wt,
        unsigned short* __restrict__ h, int M,
        const int* __restrict__ ei, int E, int N, int nps, float inv_nps,
        int* __restrict__ scursor, unsigned* __restrict__ pairs,
        int chunkSize) {
    int bid = (int)blockIdx.x;
    if (bid < NB) {
        // ---- append ----
        int sl = bid & 7;
        int total = E + N;
        int lo = bid * chunkSize;
        int hi = lo + chunkSize; if (hi > total) hi = total;
        for (int t = lo + (int)threadIdx.x; t < hi; t += 256) {
            int s, d;
            if (t < E) { s = ei[t]; d = ei[E + t]; }
            else       { s = t - E; d = s; }
            if ((unsigned)s >= (unsigned)N || (unsigned)d >= (unsigned)N) continue;
            int b = bucket_of(d, nps, inv_nps);
            int pos = atomicAdd(&scursor[sl * NB + b], 1);
            pairs[pos] = ((unsigned)s << 7) | (unsigned)(d - b * nps);
        }
        return;
    }

    // ---- MFMA GEMM: 128 rows x 128 cols per block, 4 waves x 32 rows ----
    int tid = threadIdx.x;
    int w = tid >> 6;
    int lane = tid & 63;
    int l31 = lane & 31;
    int lh = lane >> 5;
    int row0 = (bid - NB) * 128 + w * 32;

    f32x16 acc0, acc1, acc2, acc3;
#pragma unroll
    for (int i = 0; i < 16; ++i) { acc0[i] = 0.f; acc1[i] = 0.f; acc2[i] = 0.f; acc3[i] = 0.f; }

    int arow = row0 + l31;
    if (arow >= M) arow = M - 1;                   // clamp; store guarded below

    for (int k0 = 0; k0 < 128; k0 += 16) {
        int kb = k0 + lh * 8;
        float4 v0 = *(const float4*)&x[(size_t)arow * 128 + kb];
        float4 v1 = *(const float4*)&x[(size_t)arow * 128 + kb + 4];
        short8 a;
        a[0] = (short)f2bf(v0.x); a[1] = (short)f2bf(v0.y);
        a[2] = (short)f2bf(v0.z); a[3] = (short)f2bf(v0.w);
        a[4] = (short)f2bf(v1.x); a[5] = (short)f2bf(v1.y);
        a[6] = (short)f2bf(v1.z); a[7] = (short)f2bf(v1.w);

        short8 b0 = *(const short8*)&Wt[(0 * 32 + l31) * 128 + kb];
        short8 b1 = *(const short8*)&Wt[(1 * 32 + l31) * 128 + kb];
        short8 b2 = *(const short8*)&Wt[(2 * 32 + l31) * 128 + kb];
        short8 b3 = *(const short8*)&Wt[(3 * 32 + l31) * 128 + kb];
        acc0 = __builtin_amdgcn_mfma_f32_32x32x16_bf16(a, b0, acc0, 0, 0, 0);
        acc1 = __builtin_amdgcn_mfma_f32_32x32x16_bf16(a, b1, acc1, 0, 0, 0);
        acc2 = __builtin_amdgcn_mfma_f32_32x32x16_bf16(a, b2, acc2, 0, 0, 0);
        acc3 = __builtin_amdgcn_mfma_f32_32x32x16_bf16(a, b3, acc3, 0, 0, 0);
    }

    // epilogue: C/D layout col=lane&31, row=(reg&3)+8*(reg>>2)+4*(lane>>5)
#pragma unroll
    for (int reg = 0; reg < 16; ++reg) {
        int row = row0 + (reg & 3) + 8 * (reg >> 2) + 4 * lh;
        if (row < M) {
            size_t rb = (size_t)row * 128;
            h[rb +  0 + l31] = (unsigned short)f2bf(acc0[reg]);
            h[rb + 32 + l31] = (unsigned short)f2bf(acc1[reg]);
            h[rb + 64 + l31] = (unsigned short)f2bf(acc2[reg]);
            h[rb + 96 + l31] = (unsigned short)f2bf(acc3[reg]);
        }
    }
}

// ---------------- attention halves from bf16 h: as/ad[N][4] ----------------
__global__ void k_att(const unsigned short* __restrict__ h,
                      const float* __restrict__ att_s, const float* __restrict__ att_d,
                      float* __restrict__ as, float* __restrict__ ad, int N) {
    int t = blockIdx.x * 256 + threadIdx.x;
    int n = t >> 6;
    int j = t & 63;                     // uint index: dims 2j, 2j+1
    if (n >= N) return;
    unsigned u = ((const unsigned*)h)[(size_t)n * 64 + j];
    float lo = bflo(u), hi = bfhi(u);
    float ps = lo * att_s[2 * j] + hi * att_s[2 * j + 1];
    float pd = lo * att_d[2 * j] + hi * att_d[2 * j + 1];
#pragma unroll
    for (int off = 8; off >= 1; off >>= 1) {
        ps += __shfl_xor(ps, off, 64);
        pd += __shfl_xor(pd, off, 64);
    }
    if ((j & 15) == 0) {
        int hh = j >> 4;
        as[n * 4 + hh] = ps;
        ad[n * 4 + hh] = pd;
    }
}

// ---------------- bucket-local CSR (in LDS) + aggregate ----------------
__global__ __launch_bounds__(256) void k_aggb(const unsigned short* __restrict__ h,
                                              const unsigned* __restrict__ pairs,
                                              const int* __restrict__ sbase, const int* __restrict__ scnt,
                                              const float* __restrict__ as, const float* __restrict__ ad,
                                              const float* __restrict__ bias,
                                              float* __restrict__ out, int N, int nps) {
    __shared__ int csrc[2048];
    __shared__ int hist[64];
    __shared__ int rpt[65];

    int b = blockIdx.x;
    int tid = threadIdx.x;
    int dlo = b * nps;

    if (tid < nps) hist[tid] = 0;
    __syncthreads();

    // pass 1: histogram of dst-local over the 8 slice streams (clamped to LDS cap)
    int tot = 0;
#pragma unroll
    for (int xx = 0; xx < 8; ++xx) {
        int c = scnt[xx * NB + b];
        if (tot + c > 2048) c = 2048 - tot;
        tot += c;
        int st = sbase[xx * NB + b];
        for (int i = tid; i < c; i += 256)
            atomicAdd(&hist[pairs[st + i] & 127], 1);
    }
    __syncthreads();

    // exclusive scan (nps <= 64, one wave)
    if (tid < 64) {
        int v = (tid < nps) ? hist[tid] : 0;
        int acc = v;
        for (int off = 1; off < 64; off <<= 1) {
            int o = __shfl_up(acc, off, 64);
            if (tid >= off) acc += o;
        }
        rpt[tid + 1] = acc;
        if (tid == 0) rpt[0] = 0;
    }
    __syncthreads();
    if (tid < nps) hist[tid] = rpt[tid];
    __syncthreads();

    // pass 2: scatter srcs into LDS csrc
    tot = 0;
#pragma unroll
    for (int xx = 0; xx < 8; ++xx) {
        int c = scnt[xx * NB + b];
        if (tot + c > 2048) c = 2048 - tot;
        tot += c;
        int st = sbase[xx * NB + b];
        for (int i = tid; i < c; i += 256) {
            unsigned pk = pairs[st + i];
            int pos = atomicAdd(&hist[pk & 127], 1);
            csrc[pos] = (int)(pk >> 7);
        }
    }
    __syncthreads();

    // pass 3: aggregate, wave per node
    int wv = tid >> 6;
    int lane = tid & 63;
    int eo = lane >> 5;
    int q  = lane & 31;
    int head = q >> 3;
    const uint2* hp = (const uint2*)h;

    for (int dl = wv; dl < nps; dl += 4) {
        int n = dlo + dl;
        if (n >= N) break;
        int o0 = rpt[dl];
        int deg = rpt[dl + 1] - o0;
        float adh = ad[(size_t)n * 4 + head];

        float a0 = 0.f, a1 = 0.f, a2 = 0.f, a3 = 0.f, sw = 0.f;
        for (int i = eo; i < deg; i += 2) {
            int s = csrc[o0 + i];
            float e = lrelu(as[(size_t)s * 4 + head] + adh);
            float wgt = __expf(e);
            uint2 u = hp[(size_t)s * 32 + q];
            a0 = fmaf(wgt, bflo(u.x), a0);
            a1 = fmaf(wgt, bfhi(u.x), a1);
            a2 = fmaf(wgt, bflo(u.y), a2);
            a3 = fmaf(wgt, bfhi(u.y), a3);
            sw += wgt;
        }
        a0 += __shfl_xor(a0, 32, 64);
        a1 += __shfl_xor(a1, 32, 64);
        a2 += __shfl_xor(a2, 32, 64);
        a3 += __shfl_xor(a3, 32, 64);
        sw += __shfl_xor(sw, 32, 64);

        if (eo == 0) {
            float inv = 1.f / (sw + 1e-16f);
            int d0 = q * 4;
            float4 bv = *(const float4*)&bias[d0];
            float r0 = fmaf(a0, inv, bv.x);
            float r1 = fmaf(a1, inv, bv.y);
            float r2 = fmaf(a2, inv, bv.z);
            float r3 = fmaf(a3, inv, bv.w);
            r0 = r0 > 0.f ? r0 : __expf(r0) - 1.f;
            r1 = r1 > 0.f ? r1 : __expf(r1) - 1.f;
            r2 = r2 > 0.f ? r2 : __expf(r2) - 1.f;
            r3 = r3 > 0.f ? r3 : __expf(r3) - 1.f;
            *(float4*)&out[(size_t)n * 128 + d0] = make_float4(r0, r1, r2, r3);
        }
    }
}

// ---------------- launch ----------------
extern "C" void kernel_launch(void* const* d_in, const int* in_sizes, int n_in,
                              void* d_out, int out_size, void* d_ws, size_t ws_size,
                              hipStream_t stream) {
    const float* x     = (const float*)d_in[0];
    const int*   ei    = (const int*)d_in[1];     // int32 [2][E] flat
    const float* W     = (const float*)d_in[2];
    const float* att_s = (const float*)d_in[3];
    const float* att_d = (const float*)d_in[4];
    const float* bias  = (const float*)d_in[5];
    float* out = (float*)d_out;

    int N = in_sizes[0] / 128;
    int E = in_sizes[1] / 2;
    int total = E + N;

    int nps = (N + NB - 1) / NB;                  // 49 (<=64 required)
    float inv_nps = 1.0f / (float)nps;
    int chunkSize = (total + NB - 1) / NB;

    auto align256 = [](size_t v) { return (v + 255) & ~(size_t)255; };
    char* wsp = (char*)d_ws;
    size_t off = 0;
    auto alloc = [&](size_t bytes) {
        char* p = wsp + off;
        off += align256(bytes);
        return p;
    };
    unsigned short* h  = (unsigned short*)alloc((size_t)N * 128 * 2);   // 25.6 MB
    unsigned short* Wt = (unsigned short*)alloc(128 * 128 * 2);         // 32 KB
    float*    as      = (float*)alloc((size_t)N * 16);
    float*    ad      = (float*)alloc((size_t)N * 16);
    int*      scnt    = (int*)alloc((size_t)NB * NSL * 4);
    int*      sbase   = (int*)alloc((size_t)NB * NSL * 4);
    int*      scursor = (int*)alloc((size_t)NB * NSL * 4);
    unsigned* pairs   = (unsigned*)alloc((size_t)total * 4);            // dense 6.8 MB
    (void)ws_size;

    int nGemm = (N + 127) / 128;                  // 782

    k_init<<<64, 256, 0, stream>>>(W, Wt, scnt);
    k_count<<<NB, 256, 0, stream>>>(ei, E, N, nps, inv_nps, scnt, chunkSize);
    k_scan<<<1, 1024, 0, stream>>>(scnt, sbase, scursor);
    k_gemm_append<<<NB + nGemm, 256, 0, stream>>>(x, Wt, h, N, ei, E, N, nps, inv_nps,
                                                  scursor, pairs, chunkSize);
    k_att<<<(N + 3) / 4, 256, 0, stream>>>(h, att_s, att_d, as, ad, N);
    k_aggb<<<NB, 256, 0, stream>>>(h, pairs, sbase, scnt, as, ad, bias, out, N, nps);
}

// Round 11
// 226.993 us; speedup vs baseline: 1.4574x; 1.4574x over previous
//
#include <hip/hip_runtime.h>
#include <math.h>

#define NEG_SLOPE_F 0.2f
#define NB    256     // dst buckets
#define NBLK  256     // binning chunk blocks
#define OSCAP 6912    // LDS sort cap >= ceil((E+N)/NBLK)

typedef __attribute__((ext_vector_type(8)))  short short8;
typedef __attribute__((ext_vector_type(16))) float f32x16;

static __device__ __forceinline__ float lrelu(float x) {
    return x > 0.f ? x : NEG_SLOPE_F * x;
}
static __device__ __forceinline__ unsigned f2bf(float f) {
    unsigned u = __float_as_uint(f);
    unsigned r = u + 0x7FFFu + ((u >> 16) & 1u);
    return r >> 16;
}
static __device__ __forceinline__ float bflo(unsigned w) { return __uint_as_float(w << 16); }
static __device__ __forceinline__ float bfhi(unsigned w) { return __uint_as_float(w & 0xFFFF0000u); }

static __device__ __forceinline__ int bucket_of(int d, int nps, float inv_nps) {
    int b = (int)((float)d * inv_nps);
    if (d < b * nps) --b;
    else if (d >= (b + 1) * nps) ++b;
    return b;
}

// ---------------- init: W -> Wt bf16 (transposed) ----------------
__global__ void k_init(const float* __restrict__ W, unsigned short* __restrict__ Wt) {
    int g = blockIdx.x * 256 + threadIdx.x;      // 64 x 256 = 16384
    int c = g >> 7, k = g & 127;
    Wt[c * 128 + k] = (unsigned short)f2bf(W[k * 128 + c]);
}

// ---------------- pass A count: per (chunk-block, bucket) ----------------
__global__ __launch_bounds__(256) void k_countA(const int* __restrict__ ei, int E, int N,
                                                int nps, float inv_nps,
                                                int* __restrict__ cnt, int chunk) {
    __shared__ int hist[NB];
    hist[threadIdx.x] = 0;
    __syncthreads();
    int total = E + N;
    int lo = blockIdx.x * chunk;
    int hi = lo + chunk; if (hi > total) hi = total;
    for (int t = lo + (int)threadIdx.x; t < hi; t += 256) {
        int s, d;
        if (t < E) { s = ei[t]; d = ei[E + t]; }
        else       { s = t - E; d = s; }
        if ((unsigned)s >= (unsigned)N || (unsigned)d >= (unsigned)N) continue;
        atomicAdd(&hist[bucket_of(d, nps, inv_nps)], 1);
    }
    __syncthreads();
    cnt[blockIdx.x * NB + threadIdx.x] = hist[threadIdx.x];
}

// ---------------- scans: row-excl + block bases + bucket bases ----------------
// frag[i][b] = global start of block i's fragment of bucket b (block-major pairs layout)
// bucketBase[b] = global start of bucket b in csrc; bucketBase[NB] = grand total
__global__ __launch_bounds__(1024) void k_scanR(const int* __restrict__ cnt,
                                                int* __restrict__ frag,
                                                int* __restrict__ bucketBase) {
    __shared__ int sm[1024];
    __shared__ int rowTot[NBLK];
    __shared__ int blockBase[NBLK];
    int t = threadIdx.x;

    if (t < NBLK) {                       // row-exclusive scans (256 rows serial each)
        int run = 0;
        for (int b = 0; b < NB; ++b) {
            frag[t * NB + b] = run;
            run += cnt[t * NB + b];
        }
        rowTot[t] = run;
    }
    __syncthreads();

    int v = (t < NBLK) ? rowTot[t] : 0;   // scan rowTot -> blockBase
    sm[t] = v; __syncthreads();
    int acc = v;
    for (int off = 1; off < 1024; off <<= 1) {
        int o = (t >= (unsigned)off) ? sm[t - off] : 0;
        __syncthreads();
        acc += o; sm[t] = acc; __syncthreads();
    }
    if (t < NBLK) blockBase[t] = acc - v;
    if (t == NBLK - 1) bucketBase[NB] = acc;   // grand total
    __syncthreads();

    for (int p = t; p < NBLK * NB; p += 1024)  // frag += blockBase[row]
        frag[p] += blockBase[p >> 8];

    int cv = 0;                                // column (bucket) totals
    if (t < NB) {
        for (int i = 0; i < NBLK; ++i) cv += cnt[i * NB + t];
    }
    __syncthreads();
    sm[t] = (t < NB) ? cv : 0; __syncthreads();
    int acc2 = (t < NB) ? cv : 0;
    for (int off = 1; off < 1024; off <<= 1) {
        int o = (t >= (unsigned)off) ? sm[t - off] : 0;
        __syncthreads();
        acc2 += o; sm[t] = acc2; __syncthreads();
    }
    if (t < NB) bucketBase[t] = acc2 - cv;     // exclusive
}

// ---------------- fused: binA (LDS counting-sort, streaming out) + MFMA GEMM ---
__global__ __launch_bounds__(256) void k_gemm_binA(
        const float* __restrict__ x, const unsigned short* __restrict__ Wt,
        unsigned short* __restrict__ h, int M,
        const int* __restrict__ ei, int E, int N, int nps, float inv_nps,
        const int* __restrict__ frag, unsigned* __restrict__ pairs, int chunk) {
    __shared__ int cur[NB];
    __shared__ unsigned osort[OSCAP];
    int bid = (int)blockIdx.x;
    int tid = threadIdx.x;

    if (bid < NBLK) {
        // ---- binA: sort chunk by bucket in LDS, stream out contiguously ----
        int base0 = frag[bid * NB];                      // block's global start
        cur[tid] = frag[bid * NB + tid] - base0;         // local bucket starts
        __syncthreads();
        int total = E + N;
        int lo = bid * chunk;
        int hi = lo + chunk; if (hi > total) hi = total;
        for (int t = lo + tid; t < hi; t += 256) {
            int s, d;
            if (t < E) { s = ei[t]; d = ei[E + t]; }
            else       { s = t - E; d = s; }
            if ((unsigned)s >= (unsigned)N || (unsigned)d >= (unsigned)N) continue;
            int b = bucket_of(d, nps, inv_nps);
            int pos = atomicAdd(&cur[b], 1);             // LDS atomic
            osort[pos] = ((unsigned)s << 9) | (unsigned)(d - b * nps);
        }
        __syncthreads();
        int m = cur[NB - 1];                             // local count
        for (int j = tid; j < m; j += 256)
            pairs[base0 + j] = osort[j];                 // coalesced stream
        return;
    }

    // ---- MFMA GEMM: 128x128 per block, 4 waves x 32 rows ----
    int w = tid >> 6;
    int lane = tid & 63;
    int l31 = lane & 31;
    int lh = lane >> 5;
    int row0 = (bid - NBLK) * 128 + w * 32;

    f32x16 acc0, acc1, acc2, acc3;
#pragma unroll
    for (int i = 0; i < 16; ++i) { acc0[i] = 0.f; acc1[i] = 0.f; acc2[i] = 0.f; acc3[i] = 0.f; }

    int arow = row0 + l31;
    if (arow >= M) arow = M - 1;

    for (int k0 = 0; k0 < 128; k0 += 16) {
        int kb = k0 + lh * 8;
        float4 v0 = *(const float4*)&x[(size_t)arow * 128 + kb];
        float4 v1 = *(const float4*)&x[(size_t)arow * 128 + kb + 4];
        short8 a;
        a[0] = (short)f2bf(v0.x); a[1] = (short)f2bf(v0.y);
        a[2] = (short)f2bf(v0.z); a[3] = (short)f2bf(v0.w);
        a[4] = (short)f2bf(v1.x); a[5] = (short)f2bf(v1.y);
        a[6] = (short)f2bf(v1.z); a[7] = (short)f2bf(v1.w);
        short8 b0 = *(const short8*)&Wt[(0 * 32 + l31) * 128 + kb];
        short8 b1 = *(const short8*)&Wt[(1 * 32 + l31) * 128 + kb];
        short8 b2 = *(const short8*)&Wt[(2 * 32 + l31) * 128 + kb];
        short8 b3 = *(const short8*)&Wt[(3 * 32 + l31) * 128 + kb];
        acc0 = __builtin_amdgcn_mfma_f32_32x32x16_bf16(a, b0, acc0, 0, 0, 0);
        acc1 = __builtin_amdgcn_mfma_f32_32x32x16_bf16(a, b1, acc1, 0, 0, 0);
        acc2 = __builtin_amdgcn_mfma_f32_32x32x16_bf16(a, b2, acc2, 0, 0, 0);
        acc3 = __builtin_amdgcn_mfma_f32_32x32x16_bf16(a, b3, acc3, 0, 0, 0);
    }
#pragma unroll
    for (int reg = 0; reg < 16; ++reg) {
        int row = row0 + (reg & 3) + 8 * (reg >> 2) + 4 * lh;
        if (row < M) {
            size_t rb = (size_t)row * 128;
            h[rb +  0 + l31] = (unsigned short)f2bf(acc0[reg]);
            h[rb + 32 + l31] = (unsigned short)f2bf(acc1[reg]);
            h[rb + 64 + l31] = (unsigned short)f2bf(acc2[reg]);
            h[rb + 96 + l31] = (unsigned short)f2bf(acc3[reg]);
        }
    }
}

// ---------------- binB: per-bucket dst-sort -> global csrc + rowptr ----------
__global__ __launch_bounds__(512) void k_binB(const unsigned* __restrict__ pairs,
                                              const int* __restrict__ cnt, const int* __restrict__ frag,
                                              const int* __restrict__ bucketBase,
                                              int* __restrict__ csrc, int* __restrict__ rowptr,
                                              int N, int nps) {
    __shared__ int foff[NBLK];
    __shared__ int flof[NBLK + 1];
    __shared__ int hist[512];
    __shared__ int rpt[512];
    __shared__ int sm[512];

    int b = blockIdx.x;
    int t = threadIdx.x;
    int bbase = bucketBase[b];

    // fragment offsets + local prefix
    int fc = 0;
    if (t < NBLK) {
        fc = cnt[t * NB + b];
        foff[t] = frag[t * NB + b];
    }
    sm[t] = (t < NBLK) ? fc : 0;
    __syncthreads();
    int acc = (t < NBLK) ? fc : 0;
    for (int off = 1; off < 512; off <<= 1) {
        int o = (t >= (unsigned)off) ? sm[t - off] : 0;
        __syncthreads();
        acc += o; sm[t] = acc; __syncthreads();
    }
    if (t < NBLK) flof[t] = acc - fc;
    if (t == NBLK - 1) flof[NBLK] = acc;       // m = bucket edge count
    hist[t] = 0;
    __syncthreads();
    int m = flof[NBLK];

    // pass 1: histogram by dst-local
    for (int e = t; e < m; e += 512) {
        int i = 0;
#pragma unroll
        for (int stp = 128; stp; stp >>= 1)
            if (flof[i + stp] <= e) i += stp;
        unsigned pk = pairs[foff[i] + (e - flof[i])];
        atomicAdd(&hist[pk & 511], 1);
    }
    __syncthreads();

    // exclusive scan of hist (512)
    int hv = hist[t];
    sm[t] = hv;
    __syncthreads();
    int acc2 = hv;
    for (int off = 1; off < 512; off <<= 1) {
        int o = (t >= (unsigned)off) ? sm[t - off] : 0;
        __syncthreads();
        acc2 += o; sm[t] = acc2; __syncthreads();
    }
    rpt[t] = acc2 - hv;
    __syncthreads();
    hist[t] = rpt[t];                          // reuse as cursors
    __syncthreads();

    // pass 2: scatter to global csrc (bucket region written once, sequential per dst)
    for (int e = t; e < m; e += 512) {
        int i = 0;
#pragma unroll
        for (int stp = 128; stp; stp >>= 1)
            if (flof[i + stp] <= e) i += stp;
        unsigned pk = pairs[foff[i] + (e - flof[i])];
        int pos = atomicAdd(&hist[pk & 511], 1);
        csrc[bbase + pos] = (int)(pk >> 9);
    }

    // rowptr
    if (t < nps) {
        int n = b * nps + t;
        if (n < N) rowptr[n] = bbase + rpt[t];
    }
    if (b == NB - 1 && t == 0) rowptr[N] = bucketBase[NB];
}

// ---------------- attention halves from bf16 h ----------------
__global__ void k_att(const unsigned short* __restrict__ h,
                      const float* __restrict__ att_s, const float* __restrict__ att_d,
                      float* __restrict__ as, float* __restrict__ ad, int N) {
    int t = blockIdx.x * 256 + threadIdx.x;
    int n = t >> 6;
    int j = t & 63;
    if (n >= N) return;
    unsigned u = ((const unsigned*)h)[(size_t)n * 64 + j];
    float lo = bflo(u), hi = bfhi(u);
    float ps = lo * att_s[2 * j] + hi * att_s[2 * j + 1];
    float pd = lo * att_d[2 * j] + hi * att_d[2 * j + 1];
#pragma unroll
    for (int off = 8; off >= 1; off >>= 1) {
        ps += __shfl_xor(ps, off, 64);
        pd += __shfl_xor(pd, off, 64);
    }
    if ((j & 15) == 0) {
        int hh = j >> 4;
        as[n * 4 + hh] = ps;
        ad[n * 4 + hh] = pd;
    }
}

// ---------------- aggregate: one wave per node (round-6 proven) ----------------
__global__ __launch_bounds__(256) void k_agg(const unsigned short* __restrict__ h,
                                             const int* __restrict__ rowptr, const int* __restrict__ csrc,
                                             const float* __restrict__ as, const float* __restrict__ ad,
                                             const float* __restrict__ bias,
                                             float* __restrict__ out, int N) {
    int wv = threadIdx.x >> 6;
    int lane = threadIdx.x & 63;
    int n = blockIdx.x * 4 + wv;
    if (n >= N) return;
    int eo = lane >> 5;
    int q  = lane & 31;
    int head = q >> 3;

    int o0 = rowptr[n];
    int deg = rowptr[n + 1] - o0;
    float adh = ad[(size_t)n * 4 + head];

    const uint2* hp = (const uint2*)h;
    float a0 = 0.f, a1 = 0.f, a2 = 0.f, a3 = 0.f, sw = 0.f;

    for (int i = eo; i < deg; i += 2) {
        int s = csrc[o0 + i];
        float e = lrelu(as[(size_t)s * 4 + head] + adh);
        float w = __expf(e);
        uint2 u = hp[(size_t)s * 32 + q];
        a0 = fmaf(w, bflo(u.x), a0);
        a1 = fmaf(w, bfhi(u.x), a1);
        a2 = fmaf(w, bflo(u.y), a2);
        a3 = fmaf(w, bfhi(u.y), a3);
        sw += w;
    }
    a0 += __shfl_xor(a0, 32, 64);
    a1 += __shfl_xor(a1, 32, 64);
    a2 += __shfl_xor(a2, 32, 64);
    a3 += __shfl_xor(a3, 32, 64);
    sw += __shfl_xor(sw, 32, 64);

    if (eo == 0) {
        float inv = 1.f / (sw + 1e-16f);
        int d0 = q * 4;
        float4 bv = *(const float4*)&bias[d0];
        float r0 = fmaf(a0, inv, bv.x);
        float r1 = fmaf(a1, inv, bv.y);
        float r2 = fmaf(a2, inv, bv.z);
        float r3 = fmaf(a3, inv, bv.w);
        r0 = r0 > 0.f ? r0 : __expf(r0) - 1.f;
        r1 = r1 > 0.f ? r1 : __expf(r1) - 1.f;
        r2 = r2 > 0.f ? r2 : __expf(r2) - 1.f;
        r3 = r3 > 0.f ? r3 : __expf(r3) - 1.f;
        *(float4*)&out[(size_t)n * 128 + d0] = make_float4(r0, r1, r2, r3);
    }
}

// ---------------- launch ----------------
extern "C" void kernel_launch(void* const* d_in, const int* in_sizes, int n_in,
                              void* d_out, int out_size, void* d_ws, size_t ws_size,
                              hipStream_t stream) {
    const float* x     = (const float*)d_in[0];
    const int*   ei    = (const int*)d_in[1];     // int32 [2][E] flat
    const float* W     = (const float*)d_in[2];
    const float* att_s = (const float*)d_in[3];
    const float* att_d = (const float*)d_in[4];
    const float* bias  = (const float*)d_in[5];
    float* out = (float*)d_out;

    int N = in_sizes[0] / 128;
    int E = in_sizes[1] / 2;
    int total = E + N;

    int nps = (N + NB - 1) / NB;                  // 391 (<512 for 9-bit pack)
    float inv_nps = 1.0f / (float)nps;
    int chunk = (total + NBLK - 1) / NBLK;        // ~6641 (<= OSCAP)

    auto align256 = [](size_t v) { return (v + 255) & ~(size_t)255; };
    char* wsp = (char*)d_ws;
    size_t off = 0;
    auto alloc = [&](size_t bytes) {
        char* p = wsp + off;
        off += align256(bytes);
        return p;
    };
    unsigned short* h  = (unsigned short*)alloc((size_t)N * 128 * 2);
    unsigned short* Wt = (unsigned short*)alloc(128 * 128 * 2);
    float* as        = (float*)alloc((size_t)N * 16);
    float* ad        = (float*)alloc((size_t)N * 16);
    int*   cnt       = (int*)alloc((size_t)NBLK * NB * 4);
    int*   frag      = (int*)alloc((size_t)NBLK * NB * 4);
    int*   bucketBase= (int*)alloc((size_t)(NB + 1) * 4);
    unsigned* pairs  = (unsigned*)alloc((size_t)total * 4);
    int*   csrc      = (int*)alloc((size_t)total * 4);
    int*   rowptr    = (int*)alloc((size_t)(N + 1) * 4);
    (void)ws_size;

    int nGemm = (N + 127) / 128;                  // 782

    k_init<<<64, 256, 0, stream>>>(W, Wt);
    k_countA<<<NBLK, 256, 0, stream>>>(ei, E, N, nps, inv_nps, cnt, chunk);
    k_scanR<<<1, 1024, 0, stream>>>(cnt, frag, bucketBase);
    k_gemm_binA<<<NBLK + nGemm, 256, 0, stream>>>(x, Wt, h, N, ei, E, N, nps, inv_nps,
                                                  frag, pairs, chunk);
    k_binB<<<NB, 512, 0, stream>>>(pairs, cnt, frag, bucketBase, csrc, rowptr, N, nps);
    k_att<<<(N + 3) / 4, 256, 0, stream>>>(h, att_s, att_d, as, ad, N);
    k_agg<<<(N + 3) / 4, 256, 0, stream>>>(h, rowptr, csrc, as, ad, bias, out, N);
}

// Round 12
// 193.150 us; speedup vs baseline: 1.7127x; 1.1752x over previous
//
#include <hip/hip_runtime.h>
#include <math.h>

#define NEG_SLOPE_F 0.2f
#define NB    256     // dst buckets
#define NBLK  256     // binning chunk blocks
#define OSCAP 6912    // LDS sort cap >= ceil((E+N)/NBLK)

typedef __attribute__((ext_vector_type(8)))  short short8;
typedef __attribute__((ext_vector_type(16))) float f32x16;

static __device__ __forceinline__ float lrelu(float x) {
    return x > 0.f ? x : NEG_SLOPE_F * x;
}
static __device__ __forceinline__ unsigned f2bf(float f) {
    unsigned u = __float_as_uint(f);
    unsigned r = u + 0x7FFFu + ((u >> 16) & 1u);
    return r >> 16;
}
static __device__ __forceinline__ float bflo(unsigned w) { return __uint_as_float(w << 16); }
static __device__ __forceinline__ float bfhi(unsigned w) { return __uint_as_float(w & 0xFFFF0000u); }

static __device__ __forceinline__ int bucket_of(int d, int nps, float inv_nps) {
    int b = (int)((float)d * inv_nps);
    if (d < b * nps) --b;
    else if (d >= (b + 1) * nps) ++b;
    return b;
}

// ---------------- countA (+Wt init in first 64 blocks) ----------------
// Per chunk-block: LDS histogram over buckets, in-block exclusive scan.
// Outputs: cntT[b*NBLK+blk] (bucket-major), fragRow[blk*NB+b] (local excl),
// rowTot[blk].
__global__ __launch_bounds__(256) void k_countA(const float* __restrict__ W, unsigned short* __restrict__ Wt,
                                                const int* __restrict__ ei, int E, int N,
                                                int nps, float inv_nps,
                                                int* __restrict__ cntT, int* __restrict__ fragRow,
                                                int* __restrict__ rowTot, int chunk) {
    __shared__ int hist[NB];
    __shared__ int sm[NB];
    int bid = blockIdx.x, tid = threadIdx.x;
    if (bid < 64) {                                // fold in Wt transpose
        int g = bid * 256 + tid;
        int c = g >> 7, k = g & 127;
        Wt[c * 128 + k] = (unsigned short)f2bf(W[k * 128 + c]);
    }
    hist[tid] = 0;
    __syncthreads();
    int total = E + N;
    int lo = bid * chunk;
    int hi = lo + chunk; if (hi > total) hi = total;
    for (int t = lo + tid; t < hi; t += 256) {
        int s, d;
        if (t < E) { s = ei[t]; d = ei[E + t]; }
        else       { s = t - E; d = s; }
        if ((unsigned)s >= (unsigned)N || (unsigned)d >= (unsigned)N) continue;
        atomicAdd(&hist[bucket_of(d, nps, inv_nps)], 1);
    }
    __syncthreads();
    int v = hist[tid];
    sm[tid] = v;
    __syncthreads();
    int acc = v;
    for (int off = 1; off < 256; off <<= 1) {
        int o = (tid >= (unsigned)off) ? sm[tid - off] : 0;
        __syncthreads();
        acc += o; sm[tid] = acc; __syncthreads();
    }
    fragRow[bid * NB + tid] = acc - v;             // local exclusive
    cntT[tid * NBLK + bid] = v;
    if (tid == 255) rowTot[bid] = acc;
}

// ---------------- scanR: block bases, bucket bases, frag fixup ----------------
__global__ __launch_bounds__(1024) void k_scanR(const int* __restrict__ cntT,
                                                const int* __restrict__ rowTot,
                                                int* __restrict__ frag,          // fragRow in-place
                                                int* __restrict__ bucketBase) {
    __shared__ int sm[1024];
    __shared__ int blockBase[NBLK];
    int t = threadIdx.x;

    int v = (t < NBLK) ? rowTot[t] : 0;
    sm[t] = v; __syncthreads();
    int acc = v;
    for (int off = 1; off < 1024; off <<= 1) {
        int o = (t >= (unsigned)off) ? sm[t - off] : 0;
        __syncthreads();
        acc += o; sm[t] = acc; __syncthreads();
    }
    if (t < NBLK) blockBase[t] = acc - v;
    if (t == NBLK - 1) bucketBase[NB] = acc;       // grand total
    __syncthreads();

    for (int p = t; p < NBLK * NB; p += 1024)      // frag += blockBase[row]
        frag[p] += blockBase[p >> 8];

    int cv = 0;                                    // column (bucket) totals
    if (t < NB) {
        const int* row = cntT + t * NBLK;
        for (int i = 0; i < NBLK; ++i) cv += row[i];
    }
    __syncthreads();
    sm[t] = (t < NB) ? cv : 0; __syncthreads();
    int acc2 = (t < NB) ? cv : 0;
    for (int off = 1; off < 1024; off <<= 1) {
        int o = (t >= (unsigned)off) ? sm[t - off] : 0;
        __syncthreads();
        acc2 += o; sm[t] = acc2; __syncthreads();
    }
    if (t < NB) bucketBase[t] = acc2 - cv;         // exclusive
}

// ---------------- fused: binA (LDS counting-sort) + MFMA GEMM ----------------
__global__ __launch_bounds__(256) void k_gemm_binA(
        const float* __restrict__ x, const unsigned short* __restrict__ Wt,
        unsigned short* __restrict__ h, int M,
        const int* __restrict__ ei, int E, int N, int nps, float inv_nps,
        const int* __restrict__ frag, unsigned* __restrict__ pairs, int chunk) {
    __shared__ int cur[NB];
    __shared__ unsigned osort[OSCAP];
    int bid = (int)blockIdx.x;
    int tid = threadIdx.x;

    if (bid < NBLK) {
        int base0 = frag[bid * NB];
        cur[tid] = frag[bid * NB + tid] - base0;
        __syncthreads();
        int total = E + N;
        int lo = bid * chunk;
        int hi = lo + chunk; if (hi > total) hi = total;
        for (int t = lo + tid; t < hi; t += 256) {
            int s, d;
            if (t < E) { s = ei[t]; d = ei[E + t]; }
            else       { s = t - E; d = s; }
            if ((unsigned)s >= (unsigned)N || (unsigned)d >= (unsigned)N) continue;
            int b = bucket_of(d, nps, inv_nps);
            int pos = atomicAdd(&cur[b], 1);
            osort[pos] = ((unsigned)s << 9) | (unsigned)(d - b * nps);
        }
        __syncthreads();
        int m = cur[NB - 1];
        for (int j = tid; j < m; j += 256)
            pairs[base0 + j] = osort[j];
        return;
    }

    // ---- MFMA GEMM: 128x128 per block, 4 waves x 32 rows ----
    int w = tid >> 6;
    int lane = tid & 63;
    int l31 = lane & 31;
    int lh = lane >> 5;
    int row0 = (bid - NBLK) * 128 + w * 32;

    f32x16 acc0, acc1, acc2, acc3;
#pragma unroll
    for (int i = 0; i < 16; ++i) { acc0[i] = 0.f; acc1[i] = 0.f; acc2[i] = 0.f; acc3[i] = 0.f; }

    int arow = row0 + l31;
    if (arow >= M) arow = M - 1;

    for (int k0 = 0; k0 < 128; k0 += 16) {
        int kb = k0 + lh * 8;
        float4 v0 = *(const float4*)&x[(size_t)arow * 128 + kb];
        float4 v1 = *(const float4*)&x[(size_t)arow * 128 + kb + 4];
        short8 a;
        a[0] = (short)f2bf(v0.x); a[1] = (short)f2bf(v0.y);
        a[2] = (short)f2bf(v0.z); a[3] = (short)f2bf(v0.w);
        a[4] = (short)f2bf(v1.x); a[5] = (short)f2bf(v1.y);
        a[6] = (short)f2bf(v1.z); a[7] = (short)f2bf(v1.w);
        short8 b0 = *(const short8*)&Wt[(0 * 32 + l31) * 128 + kb];
        short8 b1 = *(const short8*)&Wt[(1 * 32 + l31) * 128 + kb];
        short8 b2 = *(const short8*)&Wt[(2 * 32 + l31) * 128 + kb];
        short8 b3 = *(const short8*)&Wt[(3 * 32 + l31) * 128 + kb];
        acc0 = __builtin_amdgcn_mfma_f32_32x32x16_bf16(a, b0, acc0, 0, 0, 0);
        acc1 = __builtin_amdgcn_mfma_f32_32x32x16_bf16(a, b1, acc1, 0, 0, 0);
        acc2 = __builtin_amdgcn_mfma_f32_32x32x16_bf16(a, b2, acc2, 0, 0, 0);
        acc3 = __builtin_amdgcn_mfma_f32_32x32x16_bf16(a, b3, acc3, 0, 0, 0);
    }
#pragma unroll
    for (int reg = 0; reg < 16; ++reg) {
        int row = row0 + (reg & 3) + 8 * (reg >> 2) + 4 * lh;
        if (row < M) {
            size_t rb = (size_t)row * 128;
            h[rb +  0 + l31] = (unsigned short)f2bf(acc0[reg]);
            h[rb + 32 + l31] = (unsigned short)f2bf(acc1[reg]);
            h[rb + 64 + l31] = (unsigned short)f2bf(acc2[reg]);
            h[rb + 96 + l31] = (unsigned short)f2bf(acc3[reg]);
        }
    }
}

// ---------------- fused: binB (fragment-owner threads) + att ----------------
__global__ __launch_bounds__(256) void k_binB_att(
        const unsigned* __restrict__ pairs,
        const int* __restrict__ cntT, const int* __restrict__ frag,
        const int* __restrict__ bucketBase,
        int* __restrict__ csrc, int* __restrict__ rowptr,
        const unsigned short* __restrict__ h,
        const float* __restrict__ att_s, const float* __restrict__ att_d,
        float* __restrict__ as, float* __restrict__ ad,
        int N, int nps) {
    int bid = (int)blockIdx.x;
    int t = threadIdx.x;

    if (bid >= NB) {
        // ---- att role ----
        int g = (bid - NB) * 256 + t;
        int n = g >> 6;
        int j = g & 63;
        if (n >= N) return;
        unsigned u = ((const unsigned*)h)[(size_t)n * 64 + j];
        float lo = bflo(u), hi = bfhi(u);
        float ps = lo * att_s[2 * j] + hi * att_s[2 * j + 1];
        float pd = lo * att_d[2 * j] + hi * att_d[2 * j + 1];
#pragma unroll
        for (int off = 8; off >= 1; off >>= 1) {
            ps += __shfl_xor(ps, off, 64);
            pd += __shfl_xor(pd, off, 64);
        }
        if ((j & 15) == 0) {
            int hh = j >> 4;
            as[n * 4 + hh] = ps;
            ad[n * 4 + hh] = pd;
        }
        return;
    }

    // ---- binB role: thread t owns fragment t of bucket bid ----
    __shared__ int hist[512];
    __shared__ int rpt[512];
    __shared__ int sm[256];
    int b = bid;
    int fo = frag[t * NB + b];
    int fc = cntT[b * NBLK + t];
    hist[t] = 0; hist[t + 256] = 0;
    __syncthreads();

    for (int j = 0; j < fc; ++j)
        atomicAdd(&hist[pairs[fo + j] & 511], 1);
    __syncthreads();

    // exclusive scan of hist[512] with 256 threads (pairwise)
    int e0 = hist[2 * t], e1 = hist[2 * t + 1];
    int ps2 = e0 + e1;
    sm[t] = ps2;
    __syncthreads();
    int acc = ps2;
    for (int off = 1; off < 256; off <<= 1) {
        int o = (t >= (unsigned)off) ? sm[t - off] : 0;
        __syncthreads();
        acc += o; sm[t] = acc; __syncthreads();
    }
    int excl = acc - ps2;
    rpt[2 * t] = excl;
    rpt[2 * t + 1] = excl + e0;
    __syncthreads();
    hist[t] = rpt[t]; hist[t + 256] = rpt[t + 256];   // cursors
    __syncthreads();

    int bbase = bucketBase[b];
    for (int j = 0; j < fc; ++j) {
        unsigned pk = pairs[fo + j];
        int pos = atomicAdd(&hist[pk & 511], 1);
        csrc[bbase + pos] = (int)(pk >> 9);
    }

    for (int k = t; k < nps; k += 256) {
        int n = b * nps + k;
        if (n < N) rowptr[n] = bbase + rpt[k];
    }
    if (b == NB - 1 && t == 0) rowptr[N] = bucketBase[NB];
}

// ---------------- aggregate: 4 edges in flight (quarter-wave uint4) ----------
__global__ __launch_bounds__(256) void k_agg(const unsigned short* __restrict__ h,
                                             const int* __restrict__ rowptr, const int* __restrict__ csrc,
                                             const float* __restrict__ as, const float* __restrict__ ad,
                                             const float* __restrict__ bias,
                                             float* __restrict__ out, int N) {
    int wv = threadIdx.x >> 6;
    int lane = threadIdx.x & 63;
    int n = blockIdx.x * 4 + wv;
    if (n >= N) return;
    int qt = lane >> 4;            // edge parity 0..3
    int q  = lane & 15;            // dims 8q..8q+7
    int head = q >> 2;

    int o0 = rowptr[n];
    int deg = rowptr[n + 1] - o0;
    float adh = ad[(size_t)n * 4 + head];

    const uint4* hp = (const uint4*)h;   // 16 uint4 per row
    float a0 = 0.f, a1 = 0.f, a2 = 0.f, a3 = 0.f;
    float a4 = 0.f, a5 = 0.f, a6 = 0.f, a7 = 0.f, sw = 0.f;

    for (int i = qt; i < deg; i += 4) {
        int s = csrc[o0 + i];
        float e = lrelu(as[(size_t)s * 4 + head] + adh);
        float w = __expf(e);
        uint4 u = hp[(size_t)s * 16 + q];
        a0 = fmaf(w, bflo(u.x), a0); a1 = fmaf(w, bfhi(u.x), a1);
        a2 = fmaf(w, bflo(u.y), a2); a3 = fmaf(w, bfhi(u.y), a3);
        a4 = fmaf(w, bflo(u.z), a4); a5 = fmaf(w, bfhi(u.z), a5);
        a6 = fmaf(w, bflo(u.w), a6); a7 = fmaf(w, bfhi(u.w), a7);
        sw += w;
    }
    a0 += __shfl_xor(a0, 16, 64); a0 += __shfl_xor(a0, 32, 64);
    a1 += __shfl_xor(a1, 16, 64); a1 += __shfl_xor(a1, 32, 64);
    a2 += __shfl_xor(a2, 16, 64); a2 += __shfl_xor(a2, 32, 64);
    a3 += __shfl_xor(a3, 16, 64); a3 += __shfl_xor(a3, 32, 64);
    a4 += __shfl_xor(a4, 16, 64); a4 += __shfl_xor(a4, 32, 64);
    a5 += __shfl_xor(a5, 16, 64); a5 += __shfl_xor(a5, 32, 64);
    a6 += __shfl_xor(a6, 16, 64); a6 += __shfl_xor(a6, 32, 64);
    a7 += __shfl_xor(a7, 16, 64); a7 += __shfl_xor(a7, 32, 64);
    sw += __shfl_xor(sw, 16, 64); sw += __shfl_xor(sw, 32, 64);

    if (qt == 0) {
        float inv = 1.f / (sw + 1e-16f);
        int d0 = q * 8;
        float4 b0 = *(const float4*)&bias[d0];
        float4 b1 = *(const float4*)&bias[d0 + 4];
        float r0 = fmaf(a0, inv, b0.x);
        float r1 = fmaf(a1, inv, b0.y);
        float r2 = fmaf(a2, inv, b0.z);
        float r3 = fmaf(a3, inv, b0.w);
        float r4 = fmaf(a4, inv, b1.x);
        float r5 = fmaf(a5, inv, b1.y);
        float r6 = fmaf(a6, inv, b1.z);
        float r7 = fmaf(a7, inv, b1.w);
        r0 = r0 > 0.f ? r0 : __expf(r0) - 1.f;
        r1 = r1 > 0.f ? r1 : __expf(r1) - 1.f;
        r2 = r2 > 0.f ? r2 : __expf(r2) - 1.f;
        r3 = r3 > 0.f ? r3 : __expf(r3) - 1.f;
        r4 = r4 > 0.f ? r4 : __expf(r4) - 1.f;
        r5 = r5 > 0.f ? r5 : __expf(r5) - 1.f;
        r6 = r6 > 0.f ? r6 : __expf(r6) - 1.f;
        r7 = r7 > 0.f ? r7 : __expf(r7) - 1.f;
        *(float4*)&out[(size_t)n * 128 + d0] = make_float4(r0, r1, r2, r3);
        *(float4*)&out[(size_t)n * 128 + d0 + 4] = make_float4(r4, r5, r6, r7);
    }
}

// ---------------- launch ----------------
extern "C" void kernel_launch(void* const* d_in, const int* in_sizes, int n_in,
                              void* d_out, int out_size, void* d_ws, size_t ws_size,
                              hipStream_t stream) {
    const float* x     = (const float*)d_in[0];
    const int*   ei    = (const int*)d_in[1];     // int32 [2][E] flat
    const float* W     = (const float*)d_in[2];
    const float* att_s = (const float*)d_in[3];
    const float* att_d = (const float*)d_in[4];
    const float* bias  = (const float*)d_in[5];
    float* out = (float*)d_out;

    int N = in_sizes[0] / 128;
    int E = in_sizes[1] / 2;
    int total = E + N;

    int nps = (N + NB - 1) / NB;                  // 391 (<512 for 9-bit pack)
    float inv_nps = 1.0f / (float)nps;
    int chunk = (total + NBLK - 1) / NBLK;        // ~6641 (<= OSCAP)

    auto align256 = [](size_t v) { return (v + 255) & ~(size_t)255; };
    char* wsp = (char*)d_ws;
    size_t off = 0;
    auto alloc = [&](size_t bytes) {
        char* p = wsp + off;
        off += align256(bytes);
        return p;
    };
    unsigned short* h  = (unsigned short*)alloc((size_t)N * 128 * 2);
    unsigned short* Wt = (unsigned short*)alloc(128 * 128 * 2);
    float* as        = (float*)alloc((size_t)N * 16);
    float* ad        = (float*)alloc((size_t)N * 16);
    int*   cntT      = (int*)alloc((size_t)NBLK * NB * 4);
    int*   frag      = (int*)alloc((size_t)NBLK * NB * 4);   // fragRow -> frag in-place
    int*   rowTot    = (int*)alloc((size_t)NBLK * 4);
    int*   bucketBase= (int*)alloc((size_t)(NB + 1) * 4);
    unsigned* pairs  = (unsigned*)alloc((size_t)total * 4);
    int*   csrc      = (int*)alloc((size_t)total * 4);
    int*   rowptr    = (int*)alloc((size_t)(N + 1) * 4);
    (void)ws_size;

    int nGemm = (N + 127) / 128;                  // 782
    int nAtt  = ((size_t)N * 64 + 255) / 256;     // 25000

    k_countA<<<NBLK, 256, 0, stream>>>(W, Wt, ei, E, N, nps, inv_nps, cntT, frag, rowTot, chunk);
    k_scanR<<<1, 1024, 0, stream>>>(cntT, rowTot, frag, bucketBase);
    k_gemm_binA<<<NBLK + nGemm, 256, 0, stream>>>(x, Wt, h, N, ei, E, N, nps, inv_nps,
                                                  frag, pairs, chunk);
    k_binB_att<<<NB + nAtt, 256, 0, stream>>>(pairs, cntT, frag, bucketBase, csrc, rowptr,
                                              h, att_s, att_d, as, ad, N, nps);
    k_agg<<<(N + 3) / 4, 256, 0, stream>>>(h, rowptr, csrc, as, ad, bias, out, N);
}